// Round 7
// baseline (373.777 us; speedup 1.0000x reference)
//
#include <hip/hip_runtime.h>
#include <math.h>

#define D      256
#define K      16384
#define NPTS   8192
#define DELTA  0.2f
#define LCAP   2048
#define MAXCAP 4000000u

// d_out layout (all f32): zq[8,256,32,32] | indices[8192] | bit[8,32,32,256] | loss[1]
#define O_IDX  2097152
#define O_BIT  2105344
#define O_LOSS 4202496

typedef __attribute__((ext_vector_type(8))) short bf16x8;
typedef __attribute__((ext_vector_type(4))) float f32x4;
typedef unsigned long long u64;

__device__ __forceinline__ unsigned f2s(float f) {
    unsigned u = __float_as_uint(f);
    return (u & 0x80000000u) ? ~u : (u | 0x80000000u);
}
__device__ __forceinline__ float s2f(unsigned s) {
    return __uint_as_float((s & 0x80000000u) ? (s & 0x7fffffffu) : ~s);
}
__device__ __forceinline__ unsigned short f2bf(float f) {  // RNE
    unsigned u = __float_as_uint(f);
    u += 0x7fffu + ((u >> 16) & 1u);
    return (unsigned short)(u >> 16);
}
__device__ __forceinline__ void gl2lds16(const unsigned short* g, unsigned short* l) {
    __builtin_amdgcn_global_load_lds(
        (const __attribute__((address_space(1))) void*)g,
        (__attribute__((address_space(3))) void*)l, 16, 0, 0);
}

// ---- codebook norms + bf16 normalized copy; folds state init ----
__global__ __launch_bounds__(256) void prep_codebook(const float* __restrict__ E,
                                                     float* __restrict__ den,
                                                     unsigned short* __restrict__ ewb,
                                                     unsigned* __restrict__ gmax,
                                                     u64* __restrict__ keys,
                                                     unsigned* __restrict__ cnt) {
    const int tid = threadIdx.x, lane = tid & 63, wave = tid >> 6;
    const int b = blockIdx.x;
    if (b < 32)        gmax[b * 256 + tid] = 0u;
    else if (b < 64)   keys[(b - 32) * 256 + tid] = 0ull;
    else if (b == 64 && tid < 2) cnt[tid] = 0u;
    #pragma unroll
    for (int j = 0; j < 8; ++j) {
        const int row = b * 32 + wave * 8 + j;
        const float4 v = *(const float4*)(E + (size_t)row * D + lane * 4);
        float ss = v.x * v.x + v.y * v.y + v.z * v.z + v.w * v.w;
        #pragma unroll
        for (int o = 1; o < 64; o <<= 1) ss += __shfl_xor(ss, o);
        const float dn = fmaxf(sqrtf(ss), 1e-12f);
        const unsigned lo = (unsigned)f2bf(v.x / dn) | ((unsigned)f2bf(v.y / dn) << 16);
        const unsigned hi = (unsigned)f2bf(v.z / dn) | ((unsigned)f2bf(v.w / dn) << 16);
        *(uint2*)(ewb + (size_t)row * D + lane * 4) = make_uint2(lo, hi);
        if (lane == 0) den[row] = dn;
    }
}

// ---- z [8,256,1024] -> zfb/zf32 [8192,256] ----
__global__ __launch_bounds__(256) void prep_z(const float* __restrict__ z,
                                              unsigned short* __restrict__ zfb,
                                              float* __restrict__ zf32) {
    const int bi = blockIdx.x, tid = threadIdx.x;
    const int b = bi >> 4, hw0 = (bi & 15) * 64;
    __shared__ float t[64][65];
    for (int dc = 0; dc < D; dc += 64) {
        #pragma unroll
        for (int it = 0; it < 16; ++it) {
            const int idx = it * 256 + tid;
            const int dl = idx >> 6, hw = idx & 63;
            t[dl][hw] = z[(size_t)(b * 256 + dc + dl) * 1024 + hw0 + hw];
        }
        __syncthreads();
        #pragma unroll
        for (int it = 0; it < 16; ++it) {
            const int idx = it * 256 + tid;
            const int pl = idx >> 6, dl = idx & 63;
            const float v = t[dl][pl];
            const size_t o = (size_t)(b * 1024 + hw0 + pl) * D + dc + dl;
            zfb[o]  = f2bf(v);
            zf32[o] = v;
        }
        __syncthreads();
    }
}

// ---- score: per block 128 points x 1024 codes (8 n-subs), m97 inner loop,
//      self-seeded running threshold in LDS, deferred candidate append ----
__global__ __launch_bounds__(256, 4) void score(const unsigned short* __restrict__ zfb,
                                                const unsigned short* __restrict__ ewb,
                                                u64* __restrict__ cand,
                                                unsigned* __restrict__ cnt,
                                                unsigned cap) {
    __shared__ __align__(16) unsigned short za[128 * 32];  // 8 KB
    __shared__ __align__(16) unsigned short eb[128 * 32];  // 8 KB
    __shared__ unsigned thrS[128];                          // running block max (f2s enc)
    __shared__ u64 lbuf[LCAP];                              // 16 KB
    __shared__ unsigned lcount, lbase;

    const int tid = threadIdx.x, lane = tid & 63, wave = tid >> 6;
    const int quad = lane >> 4, col = lane & 15;
    const int wm = wave >> 1, wn = wave & 1;
    const int m0 = blockIdx.x * 128;
    const int nb0 = blockIdx.y * 1024;

    if (tid < 128) thrS[tid] = 0u;
    if (tid == 0) lcount = 0u;
    // (first __syncthreads inside the chunk loop publishes these)

    const int srow = lane >> 2, schk = (lane & 3) * 8;
    const unsigned short* gA = zfb + (size_t)(m0 + wave * 32 + srow) * D + schk;
    unsigned short* lA = &za[(wave * 32) * 32];
    unsigned short* lB = &eb[(wave * 32) * 32];
    const int shsrc = lane & 48;   // col==0 lane of this 16-lane group

    for (int sub = 0; sub < 8; ++sub) {
        const unsigned short* gB =
            ewb + (size_t)(nb0 + sub * 128 + wave * 32 + srow) * D + schk;

        f32x4 acc[4][4];
        #pragma unroll
        for (int i = 0; i < 4; ++i)
            #pragma unroll
            for (int j = 0; j < 4; ++j) acc[i][j] = (f32x4){0.f, 0.f, 0.f, 0.f};

        for (int dc = 0; dc < D; dc += 32) {
            __syncthreads();
            gl2lds16(gA + dc,          lA);
            gl2lds16(gA + dc + 16 * D, lA + 16 * 32);
            gl2lds16(gB + dc,          lB);
            gl2lds16(gB + dc + 16 * D, lB + 16 * 32);
            __syncthreads();
            bf16x8 af[4], bfr[4];
            #pragma unroll
            for (int mt = 0; mt < 4; ++mt)
                af[mt] = *(const bf16x8*)&za[(wm * 64 + mt * 16 + col) * 32 + quad * 8];
            #pragma unroll
            for (int nt = 0; nt < 4; ++nt)
                bfr[nt] = *(const bf16x8*)&eb[(wn * 64 + nt * 16 + col) * 32 + quad * 8];
            #pragma unroll
            for (int mt = 0; mt < 4; ++mt)
                #pragma unroll
                for (int nt = 0; nt < 4; ++nt)
                    acc[mt][nt] = __builtin_amdgcn_mfma_f32_16x16x32_bf16(af[mt], bfr[nt],
                                                                          acc[mt][nt], 0, 0, 0);
        }

        // ---- per-sub epilogue (no barriers, no global atomics) ----
        float red[4][4];
        #pragma unroll
        for (int mt = 0; mt < 4; ++mt)
            #pragma unroll
            for (int r = 0; r < 4; ++r)
                red[mt][r] = fmaxf(fmaxf(acc[mt][0][r], acc[mt][1][r]),
                                   fmaxf(acc[mt][2][r], acc[mt][3][r]));
        #pragma unroll
        for (int off = 1; off < 16; off <<= 1)
            #pragma unroll
            for (int mt = 0; mt < 4; ++mt)
                #pragma unroll
                for (int r = 0; r < 4; ++r)
                    red[mt][r] = fmaxf(red[mt][r], __shfl_xor(red[mt][r], off));
        // update running block max (LDS atomic from col==0 lanes), broadcast threshold
        #pragma unroll
        for (int mt = 0; mt < 4; ++mt)
            #pragma unroll
            for (int r = 0; r < 4; ++r) {
                unsigned cur = 0;
                if (col == 0) {
                    const unsigned enc = f2s(red[mt][r]);
                    const unsigned old = atomicMax(&thrS[wm * 64 + mt * 16 + quad * 4 + r], enc);
                    cur = old > enc ? old : enc;
                }
                cur = (unsigned)__shfl((int)cur, shsrc);
                red[mt][r] = s2f(cur) - DELTA;      // reuse red as threshold
            }
        // append candidates (rare; individual LDS atomics)
        const int ncode0 = nb0 + sub * 128 + wn * 64 + col;
        #pragma unroll
        for (int mt = 0; mt < 4; ++mt) {
            #pragma unroll
            for (int r = 0; r < 4; ++r) {
                const float tp = red[mt][r];
                #pragma unroll
                for (int nt = 0; nt < 4; ++nt) {
                    const float v = acc[mt][nt][r];
                    if (v >= tp) {
                        const unsigned slot = atomicAdd(&lcount, 1u);
                        const unsigned pt = m0 + wm * 64 + mt * 16 + quad * 4 + r;
                        const u64 e = ((u64)((pt << 14) | (unsigned)(ncode0 + nt * 16)) << 32)
                                      | f2s(v);
                        if (slot < LCAP) lbuf[slot] = e;
                        else {
                            const unsigned g = atomicAdd(cnt, 1u);
                            if (g < cap) cand[g] = e;
                        }
                    }
                }
            }
        }
    }

    __syncthreads();
    const unsigned m_ = lcount < LCAP ? lcount : LCAP;
    if (tid == 0) lbase = atomicAdd(cnt, m_);
    __syncthreads();
    for (unsigned i = tid; i < m_; i += 256) {
        const unsigned g = lbase + i;
        if (g < cap) cand[g] = lbuf[i];
    }
}

// ---- final per-point bf16 max over candidates ----
__global__ __launch_bounds__(256) void cand_max(const u64* __restrict__ cand,
                                                const unsigned* __restrict__ cnt,
                                                unsigned* __restrict__ gmax,
                                                unsigned cap) {
    const unsigned total = min(cnt[0], cap);
    const unsigned stride = gridDim.x * 256;
    for (unsigned i = blockIdx.x * 256 + threadIdx.x; i < total; i += stride) {
        const u64 e = cand[i];
        atomicMax(&gmax[(unsigned)(e >> 46)], (unsigned)(e & 0xffffffffull));
    }
}

// ---- wave-per-candidate: filter vs final max, exact fp32 rescore ----
__global__ __launch_bounds__(256) void rescore(const float* __restrict__ zf32,
                                               const float* __restrict__ E,
                                               const float* __restrict__ den,
                                               const unsigned* __restrict__ gmax,
                                               const u64* __restrict__ cand,
                                               const unsigned* __restrict__ cnt,
                                               u64* __restrict__ keys,
                                               unsigned cap) {
    const unsigned total = min(cnt[0], cap);
    const int lane = threadIdx.x & 63;
    const unsigned w = (blockIdx.x * 256 + threadIdx.x) >> 6;
    const unsigned nw = gridDim.x * 4;
    for (unsigned i = w; i < total; i += nw) {
        const u64 e = cand[i];
        const unsigned pc = (unsigned)(e >> 32);
        const int p = pc >> 14, c = pc & 16383;
        if (s2f((unsigned)(e & 0xffffffffull)) < s2f(gmax[p]) - DELTA) continue;
        const float dinv = 1.0f / den[c];
        const float4 a = *(const float4*)(zf32 + (size_t)p * D + lane * 4);
        const float4 b = *(const float4*)(E + (size_t)c * D + lane * 4);
        float sv = fmaf(a.x, b.x * dinv, fmaf(a.y, b.y * dinv,
                   fmaf(a.z, b.z * dinv, a.w * (b.w * dinv))));
        #pragma unroll
        for (int o = 1; o < 64; o <<= 1) sv += __shfl_xor(sv, o);
        if (lane == 0)
            atomicMax(keys + p, ((u64)f2s(sv) << 32) | (unsigned)(16383 - c));
    }
}

// ---- gather + outputs (LDS transpose for coalesced zq writes) ----
__global__ __launch_bounds__(256) void finalize(const float* __restrict__ E,
                                                const float* __restrict__ den,
                                                const u64* __restrict__ keys,
                                                float* __restrict__ out) {
    __shared__ float t[32][257];
    __shared__ int sIdx[32];
    __shared__ float sDen[32];
    const int tid = threadIdx.x;
    const int n0 = blockIdx.x * 32;
    if (tid < 32) {
        const u64 key = keys[n0 + tid];
        const int idx = 16383 - (int)(unsigned)(key & 0xffffffffull);
        sIdx[tid] = idx;
        sDen[tid] = den[idx];
        out[O_IDX + n0 + tid] = (float)idx;
    }
    __syncthreads();
    const float S = 5.65685424949238019520675489683895f;  // sqrt(32)
    #pragma unroll 4
    for (int i = 0; i < 32; ++i) {
        const float v = E[(size_t)sIdx[i] * D + tid] / sDen[i];
        t[i][tid] = v;
        out[O_BIT + (size_t)(n0 + i) * D + tid] = (float)((int)(v * S) + 4);
    }
    __syncthreads();
    const int b = n0 >> 10, hw0 = n0 & 1023;
    const int hwl = tid & 31, cg = tid >> 5;
    #pragma unroll 4
    for (int cc = 0; cc < 32; ++cc) {
        const int c = cc * 8 + cg;
        out[(size_t)(b * 256 + c) * 1024 + hw0 + hwl] = t[hwl][c];
    }
    if (n0 == 0 && tid == 0) out[O_LOSS] = 0.0f;
}

extern "C" void kernel_launch(void* const* d_in, const int* in_sizes, int n_in,
                              void* d_out, int out_size, void* d_ws, size_t ws_size,
                              hipStream_t stream) {
    const float* z = (const float*)d_in[0];
    const float* E = (const float*)d_in[1];
    float* out = (float*)d_out;

    char* w = (char*)d_ws;
    unsigned short* ewb  = (unsigned short*)w;  w += (size_t)K * D * 2;      //  8 MB
    unsigned short* zfb  = (unsigned short*)w;  w += (size_t)NPTS * D * 2;   //  4 MB
    float*          zf32 = (float*)w;           w += (size_t)NPTS * D * 4;   //  8 MB
    u64*            keys = (u64*)w;             w += (size_t)NPTS * 8;       // 64 KB
    float*          den  = (float*)w;           w += (size_t)K * 4;          // 64 KB
    unsigned*       gmax = (unsigned*)w;        w += (size_t)NPTS * 4;       // 32 KB
    unsigned*       cnt  = (unsigned*)w;        w += 256;
    u64*            cand = (u64*)w;             // remainder of ws
    const size_t fixed = (size_t)(w - (char*)d_ws);
    const size_t avail = ws_size > fixed ? (ws_size - fixed) / 8 : 0;
    const unsigned cap = (unsigned)(avail < (size_t)MAXCAP ? avail : (size_t)MAXCAP);

    prep_codebook<<<K / 32, 256, 0, stream>>>(E, den, ewb, gmax, keys, cnt);
    prep_z<<<128, 256, 0, stream>>>(z, zfb, zf32);

    dim3 g1(NPTS / 128, K / 1024);   // 64 x 16 = 1024 blocks = 4/CU
    score<<<g1, 256, 0, stream>>>(zfb, ewb, cand, cnt, cap);

    cand_max<<<256, 256, 0, stream>>>(cand, cnt, gmax, cap);
    rescore<<<1024, 256, 0, stream>>>(zf32, E, den, gmax, cand, cnt, keys, cap);
    finalize<<<NPTS / 32, 256, 0, stream>>>(E, den, keys, out);
}

// Round 8
// 337.609 us; speedup vs baseline: 1.1071x; 1.1071x over previous
//
#include <hip/hip_runtime.h>
#include <math.h>

#define D      256
#define K      16384
#define NPTS   8192
#define DELTA  0.2f
#define LCAP   2048
#define MAXCAP 4000000u

// d_out layout (all f32): zq[8,256,32,32] | indices[8192] | bit[8,32,32,256] | loss[1]
#define O_IDX  2097152
#define O_BIT  2105344
#define O_LOSS 4202496

typedef __attribute__((ext_vector_type(8))) short bf16x8;
typedef __attribute__((ext_vector_type(4))) float f32x4;
typedef unsigned long long u64;

__device__ __forceinline__ unsigned f2s(float f) {
    unsigned u = __float_as_uint(f);
    return (u & 0x80000000u) ? ~u : (u | 0x80000000u);
}
__device__ __forceinline__ float s2f(unsigned s) {
    return __uint_as_float((s & 0x80000000u) ? (s & 0x7fffffffu) : ~s);
}
__device__ __forceinline__ unsigned short f2bf(float f) {  // RNE
    unsigned u = __float_as_uint(f);
    u += 0x7fffu + ((u >> 16) & 1u);
    return (unsigned short)(u >> 16);
}
__device__ __forceinline__ void gl2lds16(const unsigned short* g, unsigned short* l) {
    __builtin_amdgcn_global_load_lds(
        (const __attribute__((address_space(1))) void*)g,
        (__attribute__((address_space(3))) void*)l, 16, 0, 0);
}

// ---- codebook norms + bf16 normalized copy; folds state init ----
__global__ __launch_bounds__(256) void prep_codebook(const float* __restrict__ E,
                                                     float* __restrict__ den,
                                                     unsigned short* __restrict__ ewb,
                                                     unsigned* __restrict__ gmax,
                                                     u64* __restrict__ keys,
                                                     unsigned* __restrict__ cnt) {
    const int tid = threadIdx.x, lane = tid & 63, wave = tid >> 6;
    const int b = blockIdx.x;
    if (b < 32)        gmax[b * 256 + tid] = 0u;
    else if (b < 64)   keys[(b - 32) * 256 + tid] = 0ull;
    else if (b == 64 && tid < 2) cnt[tid] = 0u;
    #pragma unroll
    for (int j = 0; j < 8; ++j) {
        const int row = b * 32 + wave * 8 + j;
        const float4 v = *(const float4*)(E + (size_t)row * D + lane * 4);
        float ss = v.x * v.x + v.y * v.y + v.z * v.z + v.w * v.w;
        #pragma unroll
        for (int o = 1; o < 64; o <<= 1) ss += __shfl_xor(ss, o);
        const float dn = fmaxf(sqrtf(ss), 1e-12f);
        const unsigned lo = (unsigned)f2bf(v.x / dn) | ((unsigned)f2bf(v.y / dn) << 16);
        const unsigned hi = (unsigned)f2bf(v.z / dn) | ((unsigned)f2bf(v.w / dn) << 16);
        *(uint2*)(ewb + (size_t)row * D + lane * 4) = make_uint2(lo, hi);
        if (lane == 0) den[row] = dn;
    }
}

// ---- z [8,256,1024] -> zfb/zf32 [8192,256] ----
__global__ __launch_bounds__(256) void prep_z(const float* __restrict__ z,
                                              unsigned short* __restrict__ zfb,
                                              float* __restrict__ zf32) {
    const int bi = blockIdx.x, tid = threadIdx.x;
    const int b = bi >> 4, hw0 = (bi & 15) * 64;
    __shared__ float t[64][65];
    for (int dc = 0; dc < D; dc += 64) {
        #pragma unroll
        for (int it = 0; it < 16; ++it) {
            const int idx = it * 256 + tid;
            const int dl = idx >> 6, hw = idx & 63;
            t[dl][hw] = z[(size_t)(b * 256 + dc + dl) * 1024 + hw0 + hw];
        }
        __syncthreads();
        #pragma unroll
        for (int it = 0; it < 16; ++it) {
            const int idx = it * 256 + tid;
            const int pl = idx >> 6, dl = idx & 63;
            const float v = t[dl][pl];
            const size_t o = (size_t)(b * 1024 + hw0 + pl) * D + dc + dl;
            zfb[o]  = f2bf(v);
            zf32[o] = v;
        }
        __syncthreads();
    }
}

// ---- score: per block 128 points x 1024 codes (8 n-subs), m97 inner loop,
//      XCD-partitioned grid swizzle, running thresholds + cross-block gmax sharing ----
__global__ __launch_bounds__(256, 4) void score(const unsigned short* __restrict__ zfb,
                                                const unsigned short* __restrict__ ewb,
                                                unsigned* __restrict__ gmax,
                                                u64* __restrict__ cand,
                                                unsigned* __restrict__ cnt,
                                                unsigned cap) {
    __shared__ __align__(16) unsigned short za[128 * 32];  // 8 KB
    __shared__ __align__(16) unsigned short eb[128 * 32];  // 8 KB
    __shared__ unsigned thrS[128];                          // running block max (f2s enc)
    __shared__ u64 lbuf[LCAP];                              // 16 KB
    __shared__ unsigned lcount, lbase;

    const int tid = threadIdx.x, lane = tid & 63, wave = tid >> 6;
    const int quad = lane >> 4, col = lane & 15;
    const int wm = wave >> 1, wn = wave & 1;

    // XCD-partition swizzle: XCD k (= id%8, round-robin) gets y%4 == k%4, m%2 == k/4
    // -> per-XCD L2 working set = 4 n-slices (2 MB) + 32 m-tiles (2 MB) = 4 MB
    const int id   = blockIdx.x;
    const int xk   = id & 7, rest = id >> 3;
    const int yblk = (xk & 3) + 4 * (rest & 3);          // [0,16)
    const int mblk = ((xk >> 2) & 1) + 2 * (rest >> 2);  // [0,64)
    const int m0   = mblk * 128;
    const int nb0  = yblk * 1024;

    if (tid < 128) thrS[tid] = 0u;
    if (tid == 0) lcount = 0u;
    // (first __syncthreads inside the chunk loop publishes these)

    const int srow = lane >> 2, schk = (lane & 3) * 8;
    const unsigned short* gA = zfb + (size_t)(m0 + wave * 32 + srow) * D + schk;
    unsigned short* lA = &za[(wave * 32) * 32];
    unsigned short* lB = &eb[(wave * 32) * 32];
    const int shsrc = lane & 48;   // col==0 lane of this 16-lane group

    for (int sub = 0; sub < 8; ++sub) {
        const unsigned short* gB =
            ewb + (size_t)(nb0 + sub * 128 + wave * 32 + srow) * D + schk;

        f32x4 acc[4][4];
        #pragma unroll
        for (int i = 0; i < 4; ++i)
            #pragma unroll
            for (int j = 0; j < 4; ++j) acc[i][j] = (f32x4){0.f, 0.f, 0.f, 0.f};

        for (int dc = 0; dc < D; dc += 32) {
            __syncthreads();
            gl2lds16(gA + dc,          lA);        // L2-hit after first sub (swizzle)
            gl2lds16(gA + dc + 16 * D, lA + 16 * 32);
            gl2lds16(gB + dc,          lB);
            gl2lds16(gB + dc + 16 * D, lB + 16 * 32);
            __syncthreads();
            bf16x8 af[4], bfr[4];
            #pragma unroll
            for (int mt = 0; mt < 4; ++mt)
                af[mt] = *(const bf16x8*)&za[(wm * 64 + mt * 16 + col) * 32 + quad * 8];
            #pragma unroll
            for (int nt = 0; nt < 4; ++nt)
                bfr[nt] = *(const bf16x8*)&eb[(wn * 64 + nt * 16 + col) * 32 + quad * 8];
            #pragma unroll
            for (int mt = 0; mt < 4; ++mt)
                #pragma unroll
                for (int nt = 0; nt < 4; ++nt)
                    acc[mt][nt] = __builtin_amdgcn_mfma_f32_16x16x32_bf16(af[mt], bfr[nt],
                                                                          acc[mt][nt], 0, 0, 0);
        }

        // ---- per-sub epilogue (no barriers, no blocking global ops) ----
        float red[4][4];
        #pragma unroll
        for (int mt = 0; mt < 4; ++mt)
            #pragma unroll
            for (int r = 0; r < 4; ++r)
                red[mt][r] = fmaxf(fmaxf(acc[mt][0][r], acc[mt][1][r]),
                                   fmaxf(acc[mt][2][r], acc[mt][3][r]));
        #pragma unroll
        for (int off = 1; off < 16; off <<= 1)
            #pragma unroll
            for (int mt = 0; mt < 4; ++mt)
                #pragma unroll
                for (int r = 0; r < 4; ++r)
                    red[mt][r] = fmaxf(red[mt][r], __shfl_xor(red[mt][r], off));
        // update running block max (LDS atomic from col==0 lanes), broadcast threshold
        #pragma unroll
        for (int mt = 0; mt < 4; ++mt)
            #pragma unroll
            for (int r = 0; r < 4; ++r) {
                unsigned cur = 0;
                if (col == 0) {
                    const unsigned enc = f2s(red[mt][r]);
                    const unsigned old = atomicMax(&thrS[wm * 64 + mt * 16 + quad * 4 + r], enc);
                    cur = old > enc ? old : enc;
                }
                cur = (unsigned)__shfl((int)cur, shsrc);
                red[mt][r] = s2f(cur) - DELTA;      // reuse red as threshold
            }
        // append candidates (rare; individual LDS atomics)
        const int ncode0 = nb0 + sub * 128 + wn * 64 + col;
        #pragma unroll
        for (int mt = 0; mt < 4; ++mt) {
            #pragma unroll
            for (int r = 0; r < 4; ++r) {
                const float tp = red[mt][r];
                #pragma unroll
                for (int nt = 0; nt < 4; ++nt) {
                    const float v = acc[mt][nt][r];
                    if (v >= tp) {
                        const unsigned slot = atomicAdd(&lcount, 1u);
                        const unsigned pt = m0 + wm * 64 + mt * 16 + quad * 4 + r;
                        const u64 e = ((u64)((pt << 14) | (unsigned)(ncode0 + nt * 16)) << 32)
                                      | f2s(v);
                        if (slot < LCAP) lbuf[slot] = e;
                        else {
                            const unsigned g = atomicAdd(cnt, 1u);
                            if (g < cap) cand[g] = e;
                        }
                    }
                }
            }
        }
        // cross-block threshold share: fire-and-forget publish + stale peek.
        // Benign races (monotone max); stale/low values only loosen thresholds.
        if (sub < 7 && tid < 128) {
            const unsigned ru = thrS[tid];                 // may miss other waves' sub
            if (ru) atomicMax(&gmax[m0 + tid], ru);        // no return use -> non-blocking
            const unsigned g = *(volatile const unsigned*)&gmax[m0 + tid];
            if (g > ru) atomicMax(&thrS[tid], g);
        }
    }

    __syncthreads();   // all subs' thrS atomics complete
    if (tid < 128) atomicMax(&gmax[m0 + tid], thrS[tid]);  // exact block max published
    const unsigned m_ = lcount < LCAP ? lcount : LCAP;
    if (tid == 0) lbase = atomicAdd(cnt, m_);
    __syncthreads();
    for (unsigned i = tid; i < m_; i += 256) {
        const unsigned g = lbase + i;
        if (g < cap) cand[g] = lbuf[i];
    }
}

// ---- wave-per-candidate: filter vs final max, exact fp32 rescore ----
__global__ __launch_bounds__(256) void rescore(const float* __restrict__ zf32,
                                               const float* __restrict__ E,
                                               const float* __restrict__ den,
                                               const unsigned* __restrict__ gmax,
                                               const u64* __restrict__ cand,
                                               const unsigned* __restrict__ cnt,
                                               u64* __restrict__ keys,
                                               unsigned cap) {
    const unsigned total = min(cnt[0], cap);
    const int lane = threadIdx.x & 63;
    const unsigned w = (blockIdx.x * 256 + threadIdx.x) >> 6;
    const unsigned nw = gridDim.x * 4;
    for (unsigned i = w; i < total; i += nw) {
        const u64 e = cand[i];
        const unsigned pc = (unsigned)(e >> 32);
        const int p = pc >> 14, c = pc & 16383;
        if (s2f((unsigned)(e & 0xffffffffull)) < s2f(gmax[p]) - DELTA) continue;
        const float dinv = 1.0f / den[c];
        const float4 a = *(const float4*)(zf32 + (size_t)p * D + lane * 4);
        const float4 b = *(const float4*)(E + (size_t)c * D + lane * 4);
        float sv = fmaf(a.x, b.x * dinv, fmaf(a.y, b.y * dinv,
                   fmaf(a.z, b.z * dinv, a.w * (b.w * dinv))));
        #pragma unroll
        for (int o = 1; o < 64; o <<= 1) sv += __shfl_xor(sv, o);
        if (lane == 0)
            atomicMax(keys + p, ((u64)f2s(sv) << 32) | (unsigned)(16383 - c));
    }
}

// ---- gather + outputs (LDS transpose for coalesced zq writes) ----
__global__ __launch_bounds__(256) void finalize(const float* __restrict__ E,
                                                const float* __restrict__ den,
                                                const u64* __restrict__ keys,
                                                float* __restrict__ out) {
    __shared__ float t[32][257];
    __shared__ int sIdx[32];
    __shared__ float sDen[32];
    const int tid = threadIdx.x;
    const int n0 = blockIdx.x * 32;
    if (tid < 32) {
        const u64 key = keys[n0 + tid];
        const int idx = 16383 - (int)(unsigned)(key & 0xffffffffull);
        sIdx[tid] = idx;
        sDen[tid] = den[idx];
        out[O_IDX + n0 + tid] = (float)idx;
    }
    __syncthreads();
    const float S = 5.65685424949238019520675489683895f;  // sqrt(32)
    #pragma unroll 4
    for (int i = 0; i < 32; ++i) {
        const float v = E[(size_t)sIdx[i] * D + tid] / sDen[i];
        t[i][tid] = v;
        out[O_BIT + (size_t)(n0 + i) * D + tid] = (float)((int)(v * S) + 4);
    }
    __syncthreads();
    const int b = n0 >> 10, hw0 = n0 & 1023;
    const int hwl = tid & 31, cg = tid >> 5;
    #pragma unroll 4
    for (int cc = 0; cc < 32; ++cc) {
        const int c = cc * 8 + cg;
        out[(size_t)(b * 256 + c) * 1024 + hw0 + hwl] = t[hwl][c];
    }
    if (n0 == 0 && tid == 0) out[O_LOSS] = 0.0f;
}

extern "C" void kernel_launch(void* const* d_in, const int* in_sizes, int n_in,
                              void* d_out, int out_size, void* d_ws, size_t ws_size,
                              hipStream_t stream) {
    const float* z = (const float*)d_in[0];
    const float* E = (const float*)d_in[1];
    float* out = (float*)d_out;

    char* w = (char*)d_ws;
    unsigned short* ewb  = (unsigned short*)w;  w += (size_t)K * D * 2;      //  8 MB
    unsigned short* zfb  = (unsigned short*)w;  w += (size_t)NPTS * D * 2;   //  4 MB
    float*          zf32 = (float*)w;           w += (size_t)NPTS * D * 4;   //  8 MB
    u64*            keys = (u64*)w;             w += (size_t)NPTS * 8;       // 64 KB
    float*          den  = (float*)w;           w += (size_t)K * 4;          // 64 KB
    unsigned*       gmax = (unsigned*)w;        w += (size_t)NPTS * 4;       // 32 KB
    unsigned*       cnt  = (unsigned*)w;        w += 256;
    u64*            cand = (u64*)w;             // remainder of ws
    const size_t fixed = (size_t)(w - (char*)d_ws);
    const size_t avail = ws_size > fixed ? (ws_size - fixed) / 8 : 0;
    const unsigned cap = (unsigned)(avail < (size_t)MAXCAP ? avail : (size_t)MAXCAP);

    prep_codebook<<<K / 32, 256, 0, stream>>>(E, den, ewb, gmax, keys, cnt);
    prep_z<<<128, 256, 0, stream>>>(z, zfb, zf32);

    score<<<1024, 256, 0, stream>>>(zfb, ewb, gmax, cand, cnt, cap);

    rescore<<<1024, 256, 0, stream>>>(zf32, E, den, gmax, cand, cnt, keys, cap);
    finalize<<<NPTS / 32, 256, 0, stream>>>(E, den, keys, out);
}

// Round 9
// 290.264 us; speedup vs baseline: 1.2877x; 1.1631x over previous
//
#include <hip/hip_runtime.h>
#include <math.h>

#define D      256
#define K      16384
#define NPTS   8192
#define DELTA  0.2f
#define LCAP   512
#define MAXCAP 4000000u

// d_out layout (all f32): zq[8,256,32,32] | indices[8192] | bit[8,32,32,256] | loss[1]
#define O_IDX  2097152
#define O_BIT  2105344
#define O_LOSS 4202496

typedef __attribute__((ext_vector_type(8))) short bf16x8;
typedef __attribute__((ext_vector_type(4))) float f32x4;
typedef unsigned long long u64;

__device__ __forceinline__ unsigned f2s(float f) {
    unsigned u = __float_as_uint(f);
    return (u & 0x80000000u) ? ~u : (u | 0x80000000u);
}
__device__ __forceinline__ float s2f(unsigned s) {
    return __uint_as_float((s & 0x80000000u) ? (s & 0x7fffffffu) : ~s);
}
__device__ __forceinline__ unsigned short f2bf(float f) {  // RNE
    unsigned u = __float_as_uint(f);
    u += 0x7fffu + ((u >> 16) & 1u);
    return (unsigned short)(u >> 16);
}
__device__ __forceinline__ void gl2lds16(const unsigned short* g, unsigned short* l) {
    __builtin_amdgcn_global_load_lds(
        (const __attribute__((address_space(1))) void*)g,
        (__attribute__((address_space(3))) void*)l, 16, 0, 0);
}

// ---- merged prep: blocks [0,512) codebook norms+bf16; [512,640) z transpose;
//      state init folded into the first blocks ----
__global__ __launch_bounds__(256) void prep(const float* __restrict__ E,
                                            const float* __restrict__ z,
                                            float* __restrict__ den,
                                            unsigned short* __restrict__ ewb,
                                            unsigned short* __restrict__ zfb,
                                            float* __restrict__ zf32,
                                            unsigned* __restrict__ gmax,
                                            u64* __restrict__ keys,
                                            unsigned* __restrict__ cnt) {
    const int blk = blockIdx.x, tid = threadIdx.x;
    if (blk < 512) {
        const int lane = tid & 63, wave = tid >> 6;
        if (blk < 32)        gmax[blk * 256 + tid] = 0u;
        else if (blk < 64)   keys[(blk - 32) * 256 + tid] = 0ull;
        else if (blk == 64 && tid < 2) cnt[tid] = 0u;
        #pragma unroll
        for (int j = 0; j < 8; ++j) {
            const int row = blk * 32 + wave * 8 + j;
            const float4 v = *(const float4*)(E + (size_t)row * D + lane * 4);
            float ss = v.x * v.x + v.y * v.y + v.z * v.z + v.w * v.w;
            #pragma unroll
            for (int o = 1; o < 64; o <<= 1) ss += __shfl_xor(ss, o);
            const float dn = fmaxf(sqrtf(ss), 1e-12f);
            const unsigned lo = (unsigned)f2bf(v.x / dn) | ((unsigned)f2bf(v.y / dn) << 16);
            const unsigned hi = (unsigned)f2bf(v.z / dn) | ((unsigned)f2bf(v.w / dn) << 16);
            *(uint2*)(ewb + (size_t)row * D + lane * 4) = make_uint2(lo, hi);
            if (lane == 0) den[row] = dn;
        }
    } else {
        const int bi = blk - 512;
        const int b = bi >> 4, hw0 = (bi & 15) * 64;
        __shared__ float t[64][65];
        for (int dc = 0; dc < D; dc += 64) {
            #pragma unroll
            for (int it = 0; it < 16; ++it) {
                const int idx = it * 256 + tid;
                const int dl = idx >> 6, hw = idx & 63;
                t[dl][hw] = z[(size_t)(b * 256 + dc + dl) * 1024 + hw0 + hw];
            }
            __syncthreads();
            #pragma unroll
            for (int it = 0; it < 16; ++it) {
                const int idx = it * 256 + tid;
                const int pl = idx >> 6, dl = idx & 63;
                const float v = t[dl][pl];
                const size_t o = (size_t)(b * 1024 + hw0 + pl) * D + dc + dl;
                zfb[o]  = f2bf(v);
                zf32[o] = v;
            }
            __syncthreads();
        }
    }
}

// ---- score: R6-proven core. 128x128 tile, 4 waves, BK=32, x-major dispatch.
//      selfseed=1 (slices yoff..): block-local running thresholds, publish gmax at exit.
//      selfseed=0: static thresholds from gmax (read once). No in-loop global ops. ----
__global__ __launch_bounds__(256, 4) void score(const unsigned short* __restrict__ zfb,
                                                const unsigned short* __restrict__ ewb,
                                                unsigned* __restrict__ gmax,
                                                u64* __restrict__ cand,
                                                unsigned* __restrict__ cnt,
                                                unsigned cap, int yoff, int selfseed) {
    __shared__ __align__(16) unsigned short za[128 * 32];  // 8 KB
    __shared__ __align__(16) unsigned short eb[128 * 32];  // 8 KB
    __shared__ unsigned thrS[128];                          // self-seed running max
    __shared__ float thrL[128];                             // static thresholds
    __shared__ u64 lbuf[LCAP];                              // 4 KB
    __shared__ unsigned lcount, lbase;

    const int tid = threadIdx.x, lane = tid & 63, wave = tid >> 6;
    const int quad = lane >> 4, col = lane & 15;
    const int wm = wave >> 1, wn = wave & 1;
    const int m0 = blockIdx.x * 128;
    const int n0 = (yoff + blockIdx.y) * 128;

    if (selfseed) {
        if (tid < 128) thrS[tid] = 0u;
    } else {
        if (tid < 128) thrL[tid] = s2f(gmax[m0 + tid]) - DELTA;
    }
    if (tid == 0) lcount = 0u;
    // (first __syncthreads inside the chunk loop publishes these)

    const int srow = lane >> 2, schk = (lane & 3) * 8;
    const unsigned short* gA = zfb + (size_t)(m0 + wave * 32 + srow) * D + schk;
    const unsigned short* gB = ewb + (size_t)(n0 + wave * 32 + srow) * D + schk;
    unsigned short* lA = &za[(wave * 32) * 32];
    unsigned short* lB = &eb[(wave * 32) * 32];
    const int shsrc = lane & 48;   // col==0 lane of this 16-lane group

    f32x4 acc[4][4];
    #pragma unroll
    for (int i = 0; i < 4; ++i)
        #pragma unroll
        for (int j = 0; j < 4; ++j) acc[i][j] = (f32x4){0.f, 0.f, 0.f, 0.f};

    for (int dc = 0; dc < D; dc += 32) {
        __syncthreads();
        gl2lds16(gA + dc,          lA);
        gl2lds16(gA + dc + 16 * D, lA + 16 * 32);
        gl2lds16(gB + dc,          lB);
        gl2lds16(gB + dc + 16 * D, lB + 16 * 32);
        __syncthreads();
        bf16x8 af[4], bfr[4];
        #pragma unroll
        for (int mt = 0; mt < 4; ++mt)
            af[mt] = *(const bf16x8*)&za[(wm * 64 + mt * 16 + col) * 32 + quad * 8];
        #pragma unroll
        for (int nt = 0; nt < 4; ++nt)
            bfr[nt] = *(const bf16x8*)&eb[(wn * 64 + nt * 16 + col) * 32 + quad * 8];
        #pragma unroll
        for (int mt = 0; mt < 4; ++mt)
            #pragma unroll
            for (int nt = 0; nt < 4; ++nt)
                acc[mt][nt] = __builtin_amdgcn_mfma_f32_16x16x32_bf16(af[mt], bfr[nt],
                                                                      acc[mt][nt], 0, 0, 0);
    }

    // ---- epilogue ----
    float red[4][4];
    #pragma unroll
    for (int mt = 0; mt < 4; ++mt)
        #pragma unroll
        for (int r = 0; r < 4; ++r)
            red[mt][r] = fmaxf(fmaxf(acc[mt][0][r], acc[mt][1][r]),
                               fmaxf(acc[mt][2][r], acc[mt][3][r]));
    #pragma unroll
    for (int off = 1; off < 16; off <<= 1)
        #pragma unroll
        for (int mt = 0; mt < 4; ++mt)
            #pragma unroll
            for (int r = 0; r < 4; ++r)
                red[mt][r] = fmaxf(red[mt][r], __shfl_xor(red[mt][r], off));

    // thresholds: self-seed (LDS atomic running max) or static
    #pragma unroll
    for (int mt = 0; mt < 4; ++mt)
        #pragma unroll
        for (int r = 0; r < 4; ++r) {
            const int pl = wm * 64 + mt * 16 + quad * 4 + r;
            if (selfseed) {
                unsigned cur = 0;
                if (col == 0) {
                    const unsigned enc = f2s(red[mt][r]);
                    const unsigned old = atomicMax(&thrS[pl], enc);
                    cur = old > enc ? old : enc;
                }
                cur = (unsigned)__shfl((int)cur, shsrc);
                red[mt][r] = s2f(cur) - DELTA;
            } else {
                red[mt][r] = thrL[pl];
            }
        }

    // append candidates (rare; per-thread LDS atomics)
    const int ncode0 = n0 + wn * 64 + col;
    #pragma unroll
    for (int mt = 0; mt < 4; ++mt) {
        #pragma unroll
        for (int r = 0; r < 4; ++r) {
            const float tp = red[mt][r];
            const unsigned pt = m0 + wm * 64 + mt * 16 + quad * 4 + r;
            #pragma unroll
            for (int nt = 0; nt < 4; ++nt) {
                const float v = acc[mt][nt][r];
                if (v >= tp) {
                    const unsigned slot = atomicAdd(&lcount, 1u);
                    const u64 e = ((u64)((pt << 14) | (unsigned)(ncode0 + nt * 16)) << 32)
                                  | f2s(v);
                    if (slot < LCAP) lbuf[slot] = e;
                    else {
                        const unsigned g = atomicAdd(cnt, 1u);
                        if (g < cap) cand[g] = e;
                    }
                }
            }
        }
    }

    __syncthreads();
    if (selfseed && tid < 128) atomicMax(&gmax[m0 + tid], thrS[tid]);
    const unsigned m_ = lcount < LCAP ? lcount : LCAP;
    if (tid == 0) lbase = atomicAdd(cnt, m_);
    __syncthreads();
    for (unsigned i = tid; i < m_; i += 256) {
        const unsigned g = lbase + i;
        if (g < cap) cand[g] = lbuf[i];
    }
}

// ---- final per-point bf16 max over candidates ----
__global__ __launch_bounds__(256) void cand_max(const u64* __restrict__ cand,
                                                const unsigned* __restrict__ cnt,
                                                unsigned* __restrict__ gmax,
                                                unsigned cap) {
    const unsigned total = min(cnt[0], cap);
    const unsigned stride = gridDim.x * 256;
    for (unsigned i = blockIdx.x * 256 + threadIdx.x; i < total; i += stride) {
        const u64 e = cand[i];
        atomicMax(&gmax[(unsigned)(e >> 46)], (unsigned)(e & 0xffffffffull));
    }
}

// ---- lane-parallel filter + ballot-compacted wave-cooperative fp32 rescore ----
__global__ __launch_bounds__(256) void rescore(const float* __restrict__ zf32,
                                               const float* __restrict__ E,
                                               const float* __restrict__ den,
                                               const unsigned* __restrict__ gmax,
                                               const u64* __restrict__ cand,
                                               const unsigned* __restrict__ cnt,
                                               u64* __restrict__ keys,
                                               unsigned cap) {
    const unsigned total = min(cnt[0], cap);
    const int lane = threadIdx.x & 63;
    const unsigned w = (blockIdx.x * 256 + threadIdx.x) >> 6;
    const unsigned nw = gridDim.x * 4;
    for (unsigned base = w * 64; base < total; base += nw * 64) {
        const unsigned i = base + lane;
        u64 e = 0;
        bool keep = false;
        if (i < total) {
            e = cand[i];
            const int p = (int)(e >> 46);
            keep = (s2f((unsigned)(e & 0xffffffffull)) >= s2f(gmax[p]) - DELTA);
        }
        u64 mask = __ballot(keep);
        while (mask) {
            const int src = __ffsll((long long)mask) - 1;
            mask &= mask - 1;
            const unsigned pc = (unsigned)__shfl((int)(unsigned)(e >> 32), src);
            const int p = pc >> 14, c = pc & 16383;
            const float dinv = 1.0f / den[c];
            const float4 a = *(const float4*)(zf32 + (size_t)p * D + lane * 4);
            const float4 b = *(const float4*)(E + (size_t)c * D + lane * 4);
            float sv = fmaf(a.x, b.x * dinv, fmaf(a.y, b.y * dinv,
                       fmaf(a.z, b.z * dinv, a.w * (b.w * dinv))));
            #pragma unroll
            for (int o = 1; o < 64; o <<= 1) sv += __shfl_xor(sv, o);
            if (lane == 0)
                atomicMax(keys + p, ((u64)f2s(sv) << 32) | (unsigned)(16383 - c));
        }
    }
}

// ---- gather + outputs (LDS transpose for coalesced zq writes) ----
__global__ __launch_bounds__(256) void finalize(const float* __restrict__ E,
                                                const float* __restrict__ den,
                                                const u64* __restrict__ keys,
                                                float* __restrict__ out) {
    __shared__ float t[32][257];
    __shared__ int sIdx[32];
    __shared__ float sDen[32];
    const int tid = threadIdx.x;
    const int n0 = blockIdx.x * 32;
    if (tid < 32) {
        const u64 key = keys[n0 + tid];
        const int idx = 16383 - (int)(unsigned)(key & 0xffffffffull);
        sIdx[tid] = idx;
        sDen[tid] = den[idx];
        out[O_IDX + n0 + tid] = (float)idx;
    }
    __syncthreads();
    const float S = 5.65685424949238019520675489683895f;  // sqrt(32)
    #pragma unroll 4
    for (int i = 0; i < 32; ++i) {
        const float v = E[(size_t)sIdx[i] * D + tid] / sDen[i];
        t[i][tid] = v;
        out[O_BIT + (size_t)(n0 + i) * D + tid] = (float)((int)(v * S) + 4);
    }
    __syncthreads();
    const int b = n0 >> 10, hw0 = n0 & 1023;
    const int hwl = tid & 31, cg = tid >> 5;
    #pragma unroll 4
    for (int cc = 0; cc < 32; ++cc) {
        const int c = cc * 8 + cg;
        out[(size_t)(b * 256 + c) * 1024 + hw0 + hwl] = t[hwl][c];
    }
    if (n0 == 0 && tid == 0) out[O_LOSS] = 0.0f;
}

extern "C" void kernel_launch(void* const* d_in, const int* in_sizes, int n_in,
                              void* d_out, int out_size, void* d_ws, size_t ws_size,
                              hipStream_t stream) {
    const float* z = (const float*)d_in[0];
    const float* E = (const float*)d_in[1];
    float* out = (float*)d_out;

    char* w = (char*)d_ws;
    unsigned short* ewb  = (unsigned short*)w;  w += (size_t)K * D * 2;      //  8 MB
    unsigned short* zfb  = (unsigned short*)w;  w += (size_t)NPTS * D * 2;   //  4 MB
    float*          zf32 = (float*)w;           w += (size_t)NPTS * D * 4;   //  8 MB
    u64*            keys = (u64*)w;             w += (size_t)NPTS * 8;       // 64 KB
    float*          den  = (float*)w;           w += (size_t)K * 4;          // 64 KB
    unsigned*       gmax = (unsigned*)w;        w += (size_t)NPTS * 4;       // 32 KB
    unsigned*       cnt  = (unsigned*)w;        w += 256;
    u64*            cand = (u64*)w;             // remainder of ws
    const size_t fixed = (size_t)(w - (char*)d_ws);
    const size_t avail = ws_size > fixed ? (ws_size - fixed) / 8 : 0;
    const unsigned cap = (unsigned)(avail < (size_t)MAXCAP ? avail : (size_t)MAXCAP);

    prep<<<640, 256, 0, stream>>>(E, z, den, ewb, zfb, zf32, gmax, keys, cnt);

    // phase 1: slices [0,16) self-seeded, publishes per-point seed maxes
    dim3 gpre(NPTS / 128, 16);
    score<<<gpre, 256, 0, stream>>>(zfb, ewb, gmax, cand, cnt, cap, 0, 1);
    // phase 2: slices [16,128) with static seeded thresholds
    dim3 gmain(NPTS / 128, 112);
    score<<<gmain, 256, 0, stream>>>(zfb, ewb, gmax, cand, cnt, cap, 16, 0);

    cand_max<<<256, 256, 0, stream>>>(cand, cnt, gmax, cap);
    rescore<<<1024, 256, 0, stream>>>(zf32, E, den, gmax, cand, cnt, keys, cap);
    finalize<<<NPTS / 32, 256, 0, stream>>>(E, den, keys, out);
}

// Round 10
// 280.537 us; speedup vs baseline: 1.3324x; 1.0347x over previous
//
#include <hip/hip_runtime.h>
#include <math.h>

#define D      256
#define K      16384
#define NPTS   8192
#define DELTA  0.2f
#define LCAP   1024
#define MAXCAP 4000000u

// d_out layout (all f32): zq[8,256,32,32] | indices[8192] | bit[8,32,32,256] | loss[1]
#define O_IDX  2097152
#define O_BIT  2105344
#define O_LOSS 4202496

typedef __attribute__((ext_vector_type(8))) short bf16x8;
typedef __attribute__((ext_vector_type(4))) float f32x4;
typedef unsigned long long u64;

__device__ __forceinline__ unsigned f2s(float f) {
    unsigned u = __float_as_uint(f);
    return (u & 0x80000000u) ? ~u : (u | 0x80000000u);
}
__device__ __forceinline__ float s2f(unsigned s) {
    return __uint_as_float((s & 0x80000000u) ? (s & 0x7fffffffu) : ~s);
}
__device__ __forceinline__ unsigned short f2bf(float f) {  // RNE
    unsigned u = __float_as_uint(f);
    u += 0x7fffu + ((u >> 16) & 1u);
    return (unsigned short)(u >> 16);
}
__device__ __forceinline__ void gl2lds16(const unsigned short* g, unsigned short* l) {
    __builtin_amdgcn_global_load_lds(
        (const __attribute__((address_space(1))) void*)g,
        (__attribute__((address_space(3))) void*)l, 16, 0, 0);
}

// ---- merged prep: blocks [0,512) codebook norms+bf16; [512,640) z transpose;
//      state init folded into the first blocks ----
__global__ __launch_bounds__(256) void prep(const float* __restrict__ E,
                                            const float* __restrict__ z,
                                            float* __restrict__ den,
                                            unsigned short* __restrict__ ewb,
                                            unsigned short* __restrict__ zfb,
                                            float* __restrict__ zf32,
                                            unsigned* __restrict__ gmax,
                                            u64* __restrict__ keys,
                                            unsigned* __restrict__ cnt) {
    const int blk = blockIdx.x, tid = threadIdx.x;
    if (blk < 512) {
        const int lane = tid & 63, wave = tid >> 6;
        if (blk < 32)        gmax[blk * 256 + tid] = 0u;
        else if (blk < 64)   keys[(blk - 32) * 256 + tid] = 0ull;
        else if (blk == 64 && tid < 2) cnt[tid] = 0u;
        #pragma unroll
        for (int j = 0; j < 8; ++j) {
            const int row = blk * 32 + wave * 8 + j;
            const float4 v = *(const float4*)(E + (size_t)row * D + lane * 4);
            float ss = v.x * v.x + v.y * v.y + v.z * v.z + v.w * v.w;
            #pragma unroll
            for (int o = 1; o < 64; o <<= 1) ss += __shfl_xor(ss, o);
            const float dn = fmaxf(sqrtf(ss), 1e-12f);
            const unsigned lo = (unsigned)f2bf(v.x / dn) | ((unsigned)f2bf(v.y / dn) << 16);
            const unsigned hi = (unsigned)f2bf(v.z / dn) | ((unsigned)f2bf(v.w / dn) << 16);
            *(uint2*)(ewb + (size_t)row * D + lane * 4) = make_uint2(lo, hi);
            if (lane == 0) den[row] = dn;
        }
    } else {
        const int bi = blk - 512;
        const int b = bi >> 4, hw0 = (bi & 15) * 64;
        __shared__ float t[64][65];
        for (int dc = 0; dc < D; dc += 64) {
            #pragma unroll
            for (int it = 0; it < 16; ++it) {
                const int idx = it * 256 + tid;
                const int dl = idx >> 6, hw = idx & 63;
                t[dl][hw] = z[(size_t)(b * 256 + dc + dl) * 1024 + hw0 + hw];
            }
            __syncthreads();
            #pragma unroll
            for (int it = 0; it < 16; ++it) {
                const int idx = it * 256 + tid;
                const int pl = idx >> 6, dl = idx & 63;
                const float v = t[dl][pl];
                const size_t o = (size_t)(b * 1024 + hw0 + pl) * D + dc + dl;
                zfb[o]  = f2bf(v);
                zf32[o] = v;
            }
            __syncthreads();
        }
    }
}

// ================= shared GEMM core =================
// 4 waves, 2x2 wave grid, tile 128m x 128n, BK=32, 8 iters, global_load_lds staging.
#define GEMM_CORE()                                                                 \
    f32x4 acc[4][4];                                                                \
    _Pragma("unroll")                                                               \
    for (int i = 0; i < 4; ++i)                                                     \
        _Pragma("unroll")                                                           \
        for (int j = 0; j < 4; ++j) acc[i][j] = (f32x4){0.f, 0.f, 0.f, 0.f};        \
    {                                                                               \
        const int srow = lane >> 2, schk = (lane & 3) * 8;                          \
        const unsigned short* gA = zfb + (size_t)(m0 + wave * 32 + srow) * D + schk;\
        const unsigned short* gB = ewb + (size_t)(n0 + wave * 32 + srow) * D + schk;\
        unsigned short* lA = &za[(wave * 32) * 32];                                 \
        unsigned short* lB = &eb[(wave * 32) * 32];                                 \
        for (int dc = 0; dc < D; dc += 32) {                                        \
            __syncthreads();                                                        \
            gl2lds16(gA + dc,          lA);                                         \
            gl2lds16(gA + dc + 16 * D, lA + 16 * 32);                               \
            gl2lds16(gB + dc,          lB);                                         \
            gl2lds16(gB + dc + 16 * D, lB + 16 * 32);                               \
            __syncthreads();                                                        \
            bf16x8 af[4], bfr[4];                                                   \
            _Pragma("unroll")                                                       \
            for (int mt = 0; mt < 4; ++mt)                                          \
                af[mt] = *(const bf16x8*)&za[(wm * 64 + mt * 16 + col) * 32 + quad * 8]; \
            _Pragma("unroll")                                                       \
            for (int nt = 0; nt < 4; ++nt)                                          \
                bfr[nt] = *(const bf16x8*)&eb[(wn * 64 + nt * 16 + col) * 32 + quad * 8]; \
            _Pragma("unroll")                                                       \
            for (int mt = 0; mt < 4; ++mt)                                          \
                _Pragma("unroll")                                                   \
                for (int nt = 0; nt < 4; ++nt)                                      \
                    acc[mt][nt] = __builtin_amdgcn_mfma_f32_16x16x32_bf16(af[mt], bfr[nt], \
                                                                          acc[mt][nt], 0, 0, 0); \
        }                                                                           \
    }

// ---- phase 1: slices [0,16). Self-seeded block-local thresholds; publishes
//      per-point block max to gmax at exit. ----
__global__ __launch_bounds__(256, 3) void score_seed(const unsigned short* __restrict__ zfb,
                                                     const unsigned short* __restrict__ ewb,
                                                     unsigned* __restrict__ gmax,
                                                     u64* __restrict__ cand,
                                                     unsigned* __restrict__ cnt,
                                                     unsigned cap) {
    __shared__ __align__(16) unsigned short za[128 * 32];
    __shared__ __align__(16) unsigned short eb[128 * 32];
    __shared__ unsigned thrS[128];
    __shared__ u64 lbuf[LCAP];
    __shared__ unsigned lcount, lbase;

    const int tid = threadIdx.x, lane = tid & 63, wave = tid >> 6;
    const int quad = lane >> 4, col = lane & 15;
    const int wm = wave >> 1, wn = wave & 1;
    const int m0 = blockIdx.x * 128;
    const int n0 = blockIdx.y * 128;
    const int shsrc = lane & 48;

    if (tid < 128) thrS[tid] = 0u;
    if (tid == 0) lcount = 0u;

    GEMM_CORE()

    float red[4][4];
    #pragma unroll
    for (int mt = 0; mt < 4; ++mt)
        #pragma unroll
        for (int r = 0; r < 4; ++r)
            red[mt][r] = fmaxf(fmaxf(acc[mt][0][r], acc[mt][1][r]),
                               fmaxf(acc[mt][2][r], acc[mt][3][r]));
    #pragma unroll
    for (int off = 1; off < 16; off <<= 1)
        #pragma unroll
        for (int mt = 0; mt < 4; ++mt)
            #pragma unroll
            for (int r = 0; r < 4; ++r)
                red[mt][r] = fmaxf(red[mt][r], __shfl_xor(red[mt][r], off));
    #pragma unroll
    for (int mt = 0; mt < 4; ++mt)
        #pragma unroll
        for (int r = 0; r < 4; ++r) {
            const int pl = wm * 64 + mt * 16 + quad * 4 + r;
            unsigned cur = 0;
            if (col == 0) {
                const unsigned enc = f2s(red[mt][r]);
                const unsigned old = atomicMax(&thrS[pl], enc);
                cur = old > enc ? old : enc;
            }
            cur = (unsigned)__shfl((int)cur, shsrc);
            red[mt][r] = s2f(cur) - DELTA;
        }

    const int ncode0 = n0 + wn * 64 + col;
    #pragma unroll
    for (int mt = 0; mt < 4; ++mt) {
        #pragma unroll
        for (int r = 0; r < 4; ++r) {
            const float tp = red[mt][r];
            const unsigned pt = m0 + wm * 64 + mt * 16 + quad * 4 + r;
            #pragma unroll
            for (int nt = 0; nt < 4; ++nt) {
                const float v = acc[mt][nt][r];
                if (v >= tp) {
                    const unsigned slot = atomicAdd(&lcount, 1u);
                    const u64 e = ((u64)((pt << 14) | (unsigned)(ncode0 + nt * 16)) << 32)
                                  | f2s(v);
                    if (slot < LCAP) lbuf[slot] = e;
                    else {
                        const unsigned g = atomicAdd(cnt, 1u);
                        if (g < cap) cand[g] = e;
                    }
                }
            }
        }
    }

    __syncthreads();
    if (tid < 128) atomicMax(&gmax[m0 + tid], thrS[tid]);
    const unsigned m_ = lcount < LCAP ? lcount : LCAP;
    if (tid == 0) lbase = atomicAdd(cnt, m_);
    __syncthreads();
    for (unsigned i = tid; i < m_; i += 256) {
        const unsigned g = lbase + i;
        if (g < cap) cand[g] = lbuf[i];
    }
}

// ---- phase 2: slices [16,128). Static thresholds from gmax; no global ops in loop. ----
__global__ __launch_bounds__(256, 3) void score_main(const unsigned short* __restrict__ zfb,
                                                     const unsigned short* __restrict__ ewb,
                                                     const unsigned* __restrict__ gmax,
                                                     u64* __restrict__ cand,
                                                     unsigned* __restrict__ cnt,
                                                     unsigned cap) {
    __shared__ __align__(16) unsigned short za[128 * 32];
    __shared__ __align__(16) unsigned short eb[128 * 32];
    __shared__ float thrL[128];
    __shared__ u64 lbuf[LCAP];
    __shared__ unsigned lcount, lbase;

    const int tid = threadIdx.x, lane = tid & 63, wave = tid >> 6;
    const int quad = lane >> 4, col = lane & 15;
    const int wm = wave >> 1, wn = wave & 1;
    const int m0 = blockIdx.x * 128;
    const int n0 = (16 + blockIdx.y) * 128;

    if (tid < 128) thrL[tid] = s2f(gmax[m0 + tid]) - DELTA;
    if (tid == 0) lcount = 0u;

    GEMM_CORE()

    const int ncode0 = n0 + wn * 64 + col;
    #pragma unroll
    for (int mt = 0; mt < 4; ++mt) {
        #pragma unroll
        for (int r = 0; r < 4; ++r) {
            const int pl = wm * 64 + mt * 16 + quad * 4 + r;
            const float tp = thrL[pl];
            #pragma unroll
            for (int nt = 0; nt < 4; ++nt) {
                const float v = acc[mt][nt][r];
                if (v >= tp) {
                    const unsigned slot = atomicAdd(&lcount, 1u);
                    const u64 e = ((u64)(((unsigned)pl + m0) << 14 | (unsigned)(ncode0 + nt * 16)) << 32)
                                  | f2s(v);
                    if (slot < LCAP) lbuf[slot] = e;
                    else {
                        const unsigned g = atomicAdd(cnt, 1u);
                        if (g < cap) cand[g] = e;
                    }
                }
            }
        }
    }

    __syncthreads();
    const unsigned m_ = lcount < LCAP ? lcount : LCAP;
    if (tid == 0) lbase = atomicAdd(cnt, m_);
    __syncthreads();
    for (unsigned i = tid; i < m_; i += 256) {
        const unsigned g = lbase + i;
        if (g < cap) cand[g] = lbuf[i];
    }
}

// ---- final per-point bf16 max over candidates ----
__global__ __launch_bounds__(256) void cand_max(const u64* __restrict__ cand,
                                                const unsigned* __restrict__ cnt,
                                                unsigned* __restrict__ gmax,
                                                unsigned cap) {
    const unsigned total = min(cnt[0], cap);
    const unsigned stride = gridDim.x * 256;
    for (unsigned i = blockIdx.x * 256 + threadIdx.x; i < total; i += stride) {
        const u64 e = cand[i];
        atomicMax(&gmax[(unsigned)(e >> 46)], (unsigned)(e & 0xffffffffull));
    }
}

// ---- lane-parallel filter + ballot-compacted wave-cooperative fp32 rescore ----
__global__ __launch_bounds__(256) void rescore(const float* __restrict__ zf32,
                                               const float* __restrict__ E,
                                               const float* __restrict__ den,
                                               const unsigned* __restrict__ gmax,
                                               const u64* __restrict__ cand,
                                               const unsigned* __restrict__ cnt,
                                               u64* __restrict__ keys,
                                               unsigned cap) {
    const unsigned total = min(cnt[0], cap);
    const int lane = threadIdx.x & 63;
    const unsigned w = (blockIdx.x * 256 + threadIdx.x) >> 6;
    const unsigned nw = gridDim.x * 4;
    for (unsigned base = w * 64; base < total; base += nw * 64) {
        const unsigned i = base + lane;
        u64 e = 0;
        bool keep = false;
        if (i < total) {
            e = cand[i];
            const int p = (int)(e >> 46);
            keep = (s2f((unsigned)(e & 0xffffffffull)) >= s2f(gmax[p]) - DELTA);
        }
        u64 mask = __ballot(keep);
        while (mask) {
            const int src = __ffsll((long long)mask) - 1;
            mask &= mask - 1;
            const unsigned pc = (unsigned)__shfl((int)(unsigned)(e >> 32), src);
            const int p = pc >> 14, c = pc & 16383;
            const float dinv = 1.0f / den[c];
            const float4 a = *(const float4*)(zf32 + (size_t)p * D + lane * 4);
            const float4 b = *(const float4*)(E + (size_t)c * D + lane * 4);
            float sv = fmaf(a.x, b.x * dinv, fmaf(a.y, b.y * dinv,
                       fmaf(a.z, b.z * dinv, a.w * (b.w * dinv))));
            #pragma unroll
            for (int o = 1; o < 64; o <<= 1) sv += __shfl_xor(sv, o);
            if (lane == 0)
                atomicMax(keys + p, ((u64)f2s(sv) << 32) | (unsigned)(16383 - c));
        }
    }
}

// ---- gather + outputs (LDS transpose for coalesced zq writes) ----
__global__ __launch_bounds__(256) void finalize(const float* __restrict__ E,
                                                const float* __restrict__ den,
                                                const u64* __restrict__ keys,
                                                float* __restrict__ out) {
    __shared__ float t[32][257];
    __shared__ int sIdx[32];
    __shared__ float sDen[32];
    const int tid = threadIdx.x;
    const int n0 = blockIdx.x * 32;
    if (tid < 32) {
        const u64 key = keys[n0 + tid];
        const int idx = 16383 - (int)(unsigned)(key & 0xffffffffull);
        sIdx[tid] = idx;
        sDen[tid] = den[idx];
        out[O_IDX + n0 + tid] = (float)idx;
    }
    __syncthreads();
    const float S = 5.65685424949238019520675489683895f;  // sqrt(32)
    #pragma unroll 4
    for (int i = 0; i < 32; ++i) {
        const float v = E[(size_t)sIdx[i] * D + tid] / sDen[i];
        t[i][tid] = v;
        out[O_BIT + (size_t)(n0 + i) * D + tid] = (float)((int)(v * S) + 4);
    }
    __syncthreads();
    const int b = n0 >> 10, hw0 = n0 & 1023;
    const int hwl = tid & 31, cg = tid >> 5;
    #pragma unroll 4
    for (int cc = 0; cc < 32; ++cc) {
        const int c = cc * 8 + cg;
        out[(size_t)(b * 256 + c) * 1024 + hw0 + hwl] = t[hwl][c];
    }
    if (n0 == 0 && tid == 0) out[O_LOSS] = 0.0f;
}

extern "C" void kernel_launch(void* const* d_in, const int* in_sizes, int n_in,
                              void* d_out, int out_size, void* d_ws, size_t ws_size,
                              hipStream_t stream) {
    const float* z = (const float*)d_in[0];
    const float* E = (const float*)d_in[1];
    float* out = (float*)d_out;

    char* w = (char*)d_ws;
    unsigned short* ewb  = (unsigned short*)w;  w += (size_t)K * D * 2;      //  8 MB
    unsigned short* zfb  = (unsigned short*)w;  w += (size_t)NPTS * D * 2;   //  4 MB
    float*          zf32 = (float*)w;           w += (size_t)NPTS * D * 4;   //  8 MB
    u64*            keys = (u64*)w;             w += (size_t)NPTS * 8;       // 64 KB
    float*          den  = (float*)w;           w += (size_t)K * 4;          // 64 KB
    unsigned*       gmax = (unsigned*)w;        w += (size_t)NPTS * 4;       // 32 KB
    unsigned*       cnt  = (unsigned*)w;        w += 256;
    u64*            cand = (u64*)w;             // remainder of ws
    const size_t fixed = (size_t)(w - (char*)d_ws);
    const size_t avail = ws_size > fixed ? (ws_size - fixed) / 8 : 0;
    const unsigned cap = (unsigned)(avail < (size_t)MAXCAP ? avail : (size_t)MAXCAP);

    prep<<<640, 256, 0, stream>>>(E, z, den, ewb, zfb, zf32, gmax, keys, cnt);

    dim3 gpre(NPTS / 128, 16);
    score_seed<<<gpre, 256, 0, stream>>>(zfb, ewb, gmax, cand, cnt, cap);
    dim3 gmain(NPTS / 128, 112);
    score_main<<<gmain, 256, 0, stream>>>(zfb, ewb, gmax, cand, cnt, cap);

    cand_max<<<256, 256, 0, stream>>>(cand, cnt, gmax, cap);
    rescore<<<1024, 256, 0, stream>>>(zf32, E, den, gmax, cand, cnt, keys, cap);
    finalize<<<NPTS / 32, 256, 0, stream>>>(E, den, keys, out);
}

// Round 11
// 265.586 us; speedup vs baseline: 1.4074x; 1.0563x over previous
//
#include <hip/hip_runtime.h>
#include <math.h>

#define D      256
#define K      16384
#define NPTS   8192
#define DELTA  0.2f
#define LCAP   1024
#define MAXCAP 4000000u

// d_out layout (all f32): zq[8,256,32,32] | indices[8192] | bit[8,32,32,256] | loss[1]
#define O_IDX  2097152
#define O_BIT  2105344
#define O_LOSS 4202496

typedef __attribute__((ext_vector_type(8))) short bf16x8;
typedef __attribute__((ext_vector_type(4))) float f32x4;
typedef unsigned long long u64;

__device__ __forceinline__ unsigned f2s(float f) {
    unsigned u = __float_as_uint(f);
    return (u & 0x80000000u) ? ~u : (u | 0x80000000u);
}
__device__ __forceinline__ float s2f(unsigned s) {
    return __uint_as_float((s & 0x80000000u) ? (s & 0x7fffffffu) : ~s);
}
__device__ __forceinline__ unsigned short f2bf(float f) {  // RNE
    unsigned u = __float_as_uint(f);
    u += 0x7fffu + ((u >> 16) & 1u);
    return (unsigned short)(u >> 16);
}

// k-major fragment layouts: X[(k>>3)][row][k&7], 16B per (row, k-chunk)
//   zfbT: [32][NPTS][8] bf16 ; ewbT: [32][K][8] bf16

// ---- merged prep: blocks [0,512) codebook; [512,640) z transpose; state init folded ----
__global__ __launch_bounds__(256) void prep(const float* __restrict__ E,
                                            const float* __restrict__ z,
                                            float* __restrict__ den,
                                            unsigned short* __restrict__ ewbT,
                                            unsigned short* __restrict__ zfbT,
                                            float* __restrict__ zf32,
                                            unsigned* __restrict__ gmax,
                                            u64* __restrict__ keys,
                                            unsigned* __restrict__ cnt) {
    const int blk = blockIdx.x, tid = threadIdx.x;
    if (blk < 512) {
        const int lane = tid & 63, wave = tid >> 6;
        if (blk < 32)        gmax[blk * 256 + tid] = 0u;
        else if (blk < 64)   keys[(blk - 32) * 256 + tid] = 0ull;
        else if (blk == 64 && tid < 2) cnt[tid] = 0u;
        #pragma unroll
        for (int j = 0; j < 8; ++j) {
            const int row = blk * 32 + wave * 8 + j;
            const float4 v = *(const float4*)(E + (size_t)row * D + lane * 4);
            float ss = v.x * v.x + v.y * v.y + v.z * v.z + v.w * v.w;
            #pragma unroll
            for (int o = 1; o < 64; o <<= 1) ss += __shfl_xor(ss, o);
            const float dn = fmaxf(sqrtf(ss), 1e-12f);
            const unsigned lo = (unsigned)f2bf(v.x / dn) | ((unsigned)f2bf(v.y / dn) << 16);
            const unsigned hi = (unsigned)f2bf(v.z / dn) | ((unsigned)f2bf(v.w / dn) << 16);
            // k = lane*4 .. +4 -> chunk lane>>1, offset (lane&1)*4
            *(uint2*)(ewbT + ((size_t)(lane >> 1) * K + row) * 8 + (lane & 1) * 4)
                = make_uint2(lo, hi);
            if (lane == 0) den[row] = dn;
        }
    } else {
        const int bi = blk - 512;
        const int b = bi >> 4, hw0 = (bi & 15) * 64;
        __shared__ float t[64][65];
        for (int dc = 0; dc < D; dc += 64) {
            #pragma unroll
            for (int it = 0; it < 16; ++it) {
                const int idx = it * 256 + tid;
                const int dl = idx >> 6, hw = idx & 63;
                t[dl][hw] = z[(size_t)(b * 256 + dc + dl) * 1024 + hw0 + hw];
            }
            __syncthreads();
            #pragma unroll
            for (int it = 0; it < 16; ++it) {
                const int idx = it * 256 + tid;
                const int pl = idx >> 6, dl = idx & 63;
                const float v = t[dl][pl];
                const int p = b * 1024 + hw0 + pl, k = dc + dl;
                zfbT[((size_t)(k >> 3) * NPTS + p) * 8 + (k & 7)] = f2bf(v);
                zf32[(size_t)p * D + k] = v;
            }
            __syncthreads();
        }
    }
}

// ================= barrier-free GEMM core =================
// 4 waves, 2x2 wave grid, tile 128m x 128n. Fragments loaded global->VGPR from
// k-major layouts; NO LDS staging, NO barriers -> compiler pipelines with vmcnt(N).
#define GEMM_CORE()                                                                 \
    f32x4 acc[4][4];                                                                \
    _Pragma("unroll")                                                               \
    for (int i = 0; i < 4; ++i)                                                     \
        _Pragma("unroll")                                                           \
        for (int j = 0; j < 4; ++j) acc[i][j] = (f32x4){0.f, 0.f, 0.f, 0.f};        \
    {                                                                               \
        const unsigned short* pA = zfbT + ((size_t)quad * NPTS + m0 + wm * 64 + col) * 8; \
        const unsigned short* pB = ewbT + ((size_t)quad * K    + n0 + wn * 64 + col) * 8; \
        _Pragma("unroll")                                                           \
        for (int dc = 0; dc < 8; ++dc) {                                            \
            bf16x8 af[4], bfr[4];                                                   \
            _Pragma("unroll")                                                       \
            for (int mt = 0; mt < 4; ++mt)                                          \
                af[mt] = *(const bf16x8*)(pA + (size_t)dc * 4 * NPTS * 8 + mt * 128);\
            _Pragma("unroll")                                                       \
            for (int nt = 0; nt < 4; ++nt)                                          \
                bfr[nt] = *(const bf16x8*)(pB + (size_t)dc * 4 * K * 8 + nt * 128); \
            _Pragma("unroll")                                                       \
            for (int mt = 0; mt < 4; ++mt)                                          \
                _Pragma("unroll")                                                   \
                for (int nt = 0; nt < 4; ++nt)                                      \
                    acc[mt][nt] = __builtin_amdgcn_mfma_f32_16x16x32_bf16(af[mt], bfr[nt], \
                                                                          acc[mt][nt], 0, 0, 0); \
        }                                                                           \
    }

// ---- phase 1: slices [0,16). Self-seeded thresholds; publishes block max at exit. ----
__global__ __launch_bounds__(256, 3) void score_seed(const unsigned short* __restrict__ zfbT,
                                                     const unsigned short* __restrict__ ewbT,
                                                     unsigned* __restrict__ gmax,
                                                     u64* __restrict__ cand,
                                                     unsigned* __restrict__ cnt,
                                                     unsigned cap) {
    __shared__ unsigned thrS[128];
    __shared__ u64 lbuf[LCAP];
    __shared__ unsigned lcount, lbase;

    const int tid = threadIdx.x, lane = tid & 63, wave = tid >> 6;
    const int quad = lane >> 4, col = lane & 15;
    const int wm = wave >> 1, wn = wave & 1;
    const int m0 = blockIdx.x * 128;
    const int n0 = blockIdx.y * 128;
    const int shsrc = lane & 48;

    if (tid < 128) thrS[tid] = 0u;
    if (tid == 0) lcount = 0u;

    GEMM_CORE()
    __syncthreads();   // publish thrS/lcount init before epilogue

    float red[4][4];
    #pragma unroll
    for (int mt = 0; mt < 4; ++mt)
        #pragma unroll
        for (int r = 0; r < 4; ++r)
            red[mt][r] = fmaxf(fmaxf(acc[mt][0][r], acc[mt][1][r]),
                               fmaxf(acc[mt][2][r], acc[mt][3][r]));
    #pragma unroll
    for (int off = 1; off < 16; off <<= 1)
        #pragma unroll
        for (int mt = 0; mt < 4; ++mt)
            #pragma unroll
            for (int r = 0; r < 4; ++r)
                red[mt][r] = fmaxf(red[mt][r], __shfl_xor(red[mt][r], off));
    #pragma unroll
    for (int mt = 0; mt < 4; ++mt)
        #pragma unroll
        for (int r = 0; r < 4; ++r) {
            const int pl = wm * 64 + mt * 16 + quad * 4 + r;
            unsigned cur = 0;
            if (col == 0) {
                const unsigned enc = f2s(red[mt][r]);
                const unsigned old = atomicMax(&thrS[pl], enc);
                cur = old > enc ? old : enc;
            }
            cur = (unsigned)__shfl((int)cur, shsrc);
            red[mt][r] = s2f(cur) - DELTA;
        }

    const int ncode0 = n0 + wn * 64 + col;
    #pragma unroll
    for (int mt = 0; mt < 4; ++mt) {
        #pragma unroll
        for (int r = 0; r < 4; ++r) {
            const float tp = red[mt][r];
            const unsigned pt = m0 + wm * 64 + mt * 16 + quad * 4 + r;
            #pragma unroll
            for (int nt = 0; nt < 4; ++nt) {
                const float v = acc[mt][nt][r];
                if (v >= tp) {
                    const unsigned slot = atomicAdd(&lcount, 1u);
                    const u64 e = ((u64)((pt << 14) | (unsigned)(ncode0 + nt * 16)) << 32)
                                  | f2s(v);
                    if (slot < LCAP) lbuf[slot] = e;
                    else {
                        const unsigned g = atomicAdd(cnt, 1u);
                        if (g < cap) cand[g] = e;
                    }
                }
            }
        }
    }

    __syncthreads();
    if (tid < 128) atomicMax(&gmax[m0 + tid], thrS[tid]);
    const unsigned m_ = lcount < LCAP ? lcount : LCAP;
    if (tid == 0) lbase = atomicAdd(cnt, m_);
    __syncthreads();
    for (unsigned i = tid; i < m_; i += 256) {
        const unsigned g = lbase + i;
        if (g < cap) cand[g] = lbuf[i];
    }
}

// ---- phase 2: slices [16,128). Static thresholds from gmax. ----
__global__ __launch_bounds__(256, 3) void score_main(const unsigned short* __restrict__ zfbT,
                                                     const unsigned short* __restrict__ ewbT,
                                                     const unsigned* __restrict__ gmax,
                                                     u64* __restrict__ cand,
                                                     unsigned* __restrict__ cnt,
                                                     unsigned cap) {
    __shared__ float thrL[128];
    __shared__ u64 lbuf[LCAP];
    __shared__ unsigned lcount, lbase;

    const int tid = threadIdx.x, lane = tid & 63, wave = tid >> 6;
    const int quad = lane >> 4, col = lane & 15;
    const int wm = wave >> 1, wn = wave & 1;
    const int m0 = blockIdx.x * 128;
    const int n0 = (16 + blockIdx.y) * 128;

    if (tid < 128) thrL[tid] = s2f(gmax[m0 + tid]) - DELTA;
    if (tid == 0) lcount = 0u;

    GEMM_CORE()
    __syncthreads();   // publish thrL/lcount init before epilogue

    const int ncode0 = n0 + wn * 64 + col;
    #pragma unroll
    for (int mt = 0; mt < 4; ++mt) {
        #pragma unroll
        for (int r = 0; r < 4; ++r) {
            const int pl = wm * 64 + mt * 16 + quad * 4 + r;
            const float tp = thrL[pl];
            #pragma unroll
            for (int nt = 0; nt < 4; ++nt) {
                const float v = acc[mt][nt][r];
                if (v >= tp) {
                    const unsigned slot = atomicAdd(&lcount, 1u);
                    const u64 e = ((u64)(((unsigned)pl + m0) << 14 | (unsigned)(ncode0 + nt * 16)) << 32)
                                  | f2s(v);
                    if (slot < LCAP) lbuf[slot] = e;
                    else {
                        const unsigned g = atomicAdd(cnt, 1u);
                        if (g < cap) cand[g] = e;
                    }
                }
            }
        }
    }

    __syncthreads();
    const unsigned m_ = lcount < LCAP ? lcount : LCAP;
    if (tid == 0) lbase = atomicAdd(cnt, m_);
    __syncthreads();
    for (unsigned i = tid; i < m_; i += 256) {
        const unsigned g = lbase + i;
        if (g < cap) cand[g] = lbuf[i];
    }
}

// ---- final per-point bf16 max over candidates ----
__global__ __launch_bounds__(256) void cand_max(const u64* __restrict__ cand,
                                                const unsigned* __restrict__ cnt,
                                                unsigned* __restrict__ gmax,
                                                unsigned cap) {
    const unsigned total = min(cnt[0], cap);
    const unsigned stride = gridDim.x * 256;
    for (unsigned i = blockIdx.x * 256 + threadIdx.x; i < total; i += stride) {
        const u64 e = cand[i];
        atomicMax(&gmax[(unsigned)(e >> 46)], (unsigned)(e & 0xffffffffull));
    }
}

// ---- lane-parallel filter + ballot-compacted wave-cooperative fp32 rescore ----
__global__ __launch_bounds__(256) void rescore(const float* __restrict__ zf32,
                                               const float* __restrict__ E,
                                               const float* __restrict__ den,
                                               const unsigned* __restrict__ gmax,
                                               const u64* __restrict__ cand,
                                               const unsigned* __restrict__ cnt,
                                               u64* __restrict__ keys,
                                               unsigned cap) {
    const unsigned total = min(cnt[0], cap);
    const int lane = threadIdx.x & 63;
    const unsigned w = (blockIdx.x * 256 + threadIdx.x) >> 6;
    const unsigned nw = gridDim.x * 4;
    for (unsigned base = w * 64; base < total; base += nw * 64) {
        const unsigned i = base + lane;
        u64 e = 0;
        bool keep = false;
        if (i < total) {
            e = cand[i];
            const int p = (int)(e >> 46);
            keep = (s2f((unsigned)(e & 0xffffffffull)) >= s2f(gmax[p]) - DELTA);
        }
        u64 mask = __ballot(keep);
        while (mask) {
            const int src = __ffsll((long long)mask) - 1;
            mask &= mask - 1;
            const unsigned pc = (unsigned)__shfl((int)(unsigned)(e >> 32), src);
            const int p = pc >> 14, c = pc & 16383;
            const float dinv = 1.0f / den[c];
            const float4 a = *(const float4*)(zf32 + (size_t)p * D + lane * 4);
            const float4 b = *(const float4*)(E + (size_t)c * D + lane * 4);
            float sv = fmaf(a.x, b.x * dinv, fmaf(a.y, b.y * dinv,
                       fmaf(a.z, b.z * dinv, a.w * (b.w * dinv))));
            #pragma unroll
            for (int o = 1; o < 64; o <<= 1) sv += __shfl_xor(sv, o);
            if (lane == 0)
                atomicMax(keys + p, ((u64)f2s(sv) << 32) | (unsigned)(16383 - c));
        }
    }
}

// ---- gather + outputs (LDS transpose for coalesced zq writes) ----
__global__ __launch_bounds__(256) void finalize(const float* __restrict__ E,
                                                const float* __restrict__ den,
                                                const u64* __restrict__ keys,
                                                float* __restrict__ out) {
    __shared__ float t[32][257];
    __shared__ int sIdx[32];
    __shared__ float sDen[32];
    const int tid = threadIdx.x;
    const int n0 = blockIdx.x * 32;
    if (tid < 32) {
        const u64 key = keys[n0 + tid];
        const int idx = 16383 - (int)(unsigned)(key & 0xffffffffull);
        sIdx[tid] = idx;
        sDen[tid] = den[idx];
        out[O_IDX + n0 + tid] = (float)idx;
    }
    __syncthreads();
    const float S = 5.65685424949238019520675489683895f;  // sqrt(32)
    #pragma unroll 4
    for (int i = 0; i < 32; ++i) {
        const float v = E[(size_t)sIdx[i] * D + tid] / sDen[i];
        t[i][tid] = v;
        out[O_BIT + (size_t)(n0 + i) * D + tid] = (float)((int)(v * S) + 4);
    }
    __syncthreads();
    const int b = n0 >> 10, hw0 = n0 & 1023;
    const int hwl = tid & 31, cg = tid >> 5;
    #pragma unroll 4
    for (int cc = 0; cc < 32; ++cc) {
        const int c = cc * 8 + cg;
        out[(size_t)(b * 256 + c) * 1024 + hw0 + hwl] = t[hwl][c];
    }
    if (n0 == 0 && tid == 0) out[O_LOSS] = 0.0f;
}

extern "C" void kernel_launch(void* const* d_in, const int* in_sizes, int n_in,
                              void* d_out, int out_size, void* d_ws, size_t ws_size,
                              hipStream_t stream) {
    const float* z = (const float*)d_in[0];
    const float* E = (const float*)d_in[1];
    float* out = (float*)d_out;

    char* w = (char*)d_ws;
    unsigned short* ewbT = (unsigned short*)w;  w += (size_t)K * D * 2;      //  8 MB
    unsigned short* zfbT = (unsigned short*)w;  w += (size_t)NPTS * D * 2;   //  4 MB
    float*          zf32 = (float*)w;           w += (size_t)NPTS * D * 4;   //  8 MB
    u64*            keys = (u64*)w;             w += (size_t)NPTS * 8;       // 64 KB
    float*          den  = (float*)w;           w += (size_t)K * 4;          // 64 KB
    unsigned*       gmax = (unsigned*)w;        w += (size_t)NPTS * 4;       // 32 KB
    unsigned*       cnt  = (unsigned*)w;        w += 256;
    u64*            cand = (u64*)w;             // remainder of ws
    const size_t fixed = (size_t)(w - (char*)d_ws);
    const size_t avail = ws_size > fixed ? (ws_size - fixed) / 8 : 0;
    const unsigned cap = (unsigned)(avail < (size_t)MAXCAP ? avail : (size_t)MAXCAP);

    prep<<<640, 256, 0, stream>>>(E, z, den, ewbT, zfbT, zf32, gmax, keys, cnt);

    dim3 gpre(NPTS / 128, 16);
    score_seed<<<gpre, 256, 0, stream>>>(zfbT, ewbT, gmax, cand, cnt, cap);
    dim3 gmain(NPTS / 128, 112);
    score_main<<<gmain, 256, 0, stream>>>(zfbT, ewbT, gmax, cand, cnt, cap);

    cand_max<<<256, 256, 0, stream>>>(cand, cnt, gmax, cap);
    rescore<<<1024, 256, 0, stream>>>(zf32, E, den, gmax, cand, cnt, keys, cap);
    finalize<<<NPTS / 32, 256, 0, stream>>>(E, den, keys, out);
}